// Round 1
// baseline (291.806 us; speedup 1.0000x reference)
//
#include <hip/hip_runtime.h>
#include <hip/hip_bf16.h>

typedef __attribute__((ext_vector_type(4))) float f32x4;
typedef __attribute__((ext_vector_type(8))) short bf16x8;

#define GBL_AS(p) (const __attribute__((address_space(1))) void*)(p)
#define LDS_AS(p) (__attribute__((address_space(3))) void*)(p)

__device__ __forceinline__ void gload_lds16(const void* g, void* l) {
  __builtin_amdgcn_global_load_lds(GBL_AS(g), LDS_AS(l), 16, 0, 0);
}

__device__ __forceinline__ ushort f2bf(float f) {
  union { float f; unsigned int u; } v; v.f = f;
  unsigned int r = v.u + 0x7fffu + ((v.u >> 16) & 1u);
  return (ushort)(r >> 16);
}

// ---------------------------------------------------------------- cast f32->bf16
__global__ void cast_f32_bf16_kernel(const float4* __restrict__ in,
                                     ushort4* __restrict__ out, int n4) {
  int i = blockIdx.x * 256 + threadIdx.x;
  if (i < n4) {
    float4 v = in[i];
    ushort4 o;
    o.x = f2bf(v.x); o.y = f2bf(v.y); o.z = f2bf(v.z); o.w = f2bf(v.w);
    out[i] = o;
  }
}

// ------------------------------------------------- transpose + cast: [R][C]f32 -> [C][R]bf16
__global__ void transpose_cast_kernel(const float* __restrict__ in,
                                      ushort* __restrict__ out, int R, int C) {
  __shared__ float tile[64][65];
  int tx = threadIdx.x & 63, ty = threadIdx.x >> 6;
  int r0 = blockIdx.y * 64, c0 = blockIdx.x * 64;
#pragma unroll
  for (int i = 0; i < 64; i += 4)
    tile[ty + i][tx] = in[(size_t)(r0 + ty + i) * C + (c0 + tx)];
  __syncthreads();
#pragma unroll
  for (int i = 0; i < 64; i += 4)
    out[(size_t)(c0 + ty + i) * R + (r0 + tx)] = f2bf(tile[tx][ty + i]);
}

// ---------------------------------------------------------------- bf16 GEMM, Bt layout
// A: [M][K] bf16, Bt: [N][K] bf16.  MODE 0: C=f32 [M][N] + bias.
// MODE 1: QKV scatter: Q scaled by 1/sqrt(128) -> [B*H][S][D]; K -> [B*H][S][D];
//         V -> transposed [B*H][D][S].  (HIDDEN=2048, H=16, D=128, S=2048 hard-coded)
template <int MODE>
__global__ __launch_bounds__(256, 2) void gemm_bt_kernel(
    const ushort* __restrict__ A, const ushort* __restrict__ Bt,
    const float* __restrict__ bias, float* __restrict__ C,
    ushort* __restrict__ Qo, ushort* __restrict__ Ko, ushort* __restrict__ Vo,
    int M, int N, int K) {
  __shared__ ushort As[128 * 64];
  __shared__ ushort Bs[128 * 64];
  const int tid = threadIdx.x;
  const int w = tid >> 6, l = tid & 63;
  const int wr = w >> 1, wc = w & 1;
  const int m0 = blockIdx.y * 128, n0 = blockIdx.x * 128;

  f32x4 acc[4][4] = {};

  const int lr = l >> 3;             // row-in-1KB-group (0..7)
  const int lc = (l & 7) ^ lr;       // pre-swizzled source chunk

  for (int k0 = 0; k0 < K; k0 += 64) {
#pragma unroll
    for (int i = 0; i < 4; ++i) {
      int row = i * 32 + w * 8 + lr;
      gload_lds16(A + (size_t)(m0 + row) * K + k0 + lc * 8,
                  (char*)As + (i * 32 + w * 8) * 128);
      gload_lds16(Bt + (size_t)(n0 + row) * K + k0 + lc * 8,
                  (char*)Bs + (i * 32 + w * 8) * 128);
    }
    __syncthreads();
    const char* Ab = (const char*)As;
    const char* Bb = (const char*)Bs;
#pragma unroll
    for (int ks = 0; ks < 2; ++ks) {
      bf16x8 af[4], bfr[4];
      int cc = ks * 4 + (l >> 4);
#pragma unroll
      for (int mi = 0; mi < 4; ++mi) {
        int row = wr * 64 + mi * 16 + (l & 15);
        af[mi] = *(const bf16x8*)(Ab + row * 128 + ((cc ^ (row & 7)) << 4));
      }
#pragma unroll
      for (int ni = 0; ni < 4; ++ni) {
        int row = wc * 64 + ni * 16 + (l & 15);
        bfr[ni] = *(const bf16x8*)(Bb + row * 128 + ((cc ^ (row & 7)) << 4));
      }
#pragma unroll
      for (int mi = 0; mi < 4; ++mi)
#pragma unroll
        for (int ni = 0; ni < 4; ++ni)
          acc[mi][ni] = __builtin_amdgcn_mfma_f32_16x16x32_bf16(
              af[mi], bfr[ni], acc[mi][ni], 0, 0, 0);
    }
    __syncthreads();
  }

  if (MODE == 0) {
#pragma unroll
    for (int mi = 0; mi < 4; ++mi) {
      int row = m0 + wr * 64 + mi * 16 + ((l >> 4) << 2);
#pragma unroll
      for (int ni = 0; ni < 4; ++ni) {
        int col = n0 + wc * 64 + ni * 16 + (l & 15);
        float b = bias[col];
#pragma unroll
        for (int r = 0; r < 4; ++r)
          C[(size_t)(row + r) * N + col] = acc[mi][ni][r] + b;
      }
    }
  } else {
    const float qscale = 0.08838834764831845f;  // 1/sqrt(128)
#pragma unroll
    for (int ni = 0; ni < 4; ++ni) {
      int n = n0 + wc * 64 + ni * 16 + (l & 15);
      int which = n >> 11;
      int cc2 = n & 2047;
      int h = cc2 >> 7, d = cc2 & 127;
      float b = bias[n];
#pragma unroll
      for (int mi = 0; mi < 4; ++mi) {
        int m = m0 + wr * 64 + mi * 16 + ((l >> 4) << 2);
        int bb = m >> 11, s = m & 2047;
        int bh = bb * 16 + h;
        if (which == 0) {
#pragma unroll
          for (int r = 0; r < 4; ++r)
            Qo[((size_t)bh * 2048 + s + r) * 128 + d] =
                f2bf((acc[mi][ni][r] + b) * qscale);
        } else if (which == 1) {
#pragma unroll
          for (int r = 0; r < 4; ++r)
            Ko[((size_t)bh * 2048 + s + r) * 128 + d] = f2bf(acc[mi][ni][r] + b);
        } else {
          ushort4 pk;
          pk.x = f2bf(acc[mi][ni][0] + b);
          pk.y = f2bf(acc[mi][ni][1] + b);
          pk.z = f2bf(acc[mi][ni][2] + b);
          pk.w = f2bf(acc[mi][ni][3] + b);
          *(ushort4*)(Vo + ((size_t)bh * 128 + d) * 2048 + s) = pk;
        }
      }
    }
  }
}

// ---------------------------------------------------------------- flash attention
// Q,K: [B*H][S][D] bf16 (Q pre-scaled);  Vt: [B*H][D][S] bf16.
// Out: combined [B][S][H*D] bf16.
__global__ __launch_bounds__(256, 2) void attn_kernel(
    const ushort* __restrict__ Qg, const ushort* __restrict__ Kg,
    const ushort* __restrict__ Vtg, ushort* __restrict__ Og) {
  constexpr int S = 2048, D = 128;
  __shared__ ushort Kl[64 * 128];     // [kv][d], 256B rows, swizzled
  __shared__ ushort Vl[128 * 64];     // [d][kv], 128B rows, swizzled
  __shared__ ushort Pl[4][32 * 64];   // per-wave P, swizzled

  const int tid = threadIdx.x, w = tid >> 6, l = tid & 63;
  const int bh = blockIdx.y;
  const int qb = 15 - (int)blockIdx.x;   // heavy blocks first
  const int q0 = qb * 128, wq0 = q0 + w * 32;

  const ushort* Qb = Qg + (size_t)bh * S * D;
  const ushort* Kb = Kg + (size_t)bh * S * D;
  const ushort* Vb = Vtg + (size_t)bh * D * S;

  bf16x8 qf[2][4];
#pragma unroll
  for (int rg = 0; rg < 2; ++rg)
#pragma unroll
    for (int ks = 0; ks < 4; ++ks)
      qf[rg][ks] = *(const bf16x8*)(Qb + (size_t)(wq0 + rg * 16 + (l & 15)) * D +
                                    ks * 32 + (l >> 4) * 8);

  f32x4 o[2][8] = {};
  float mrun[8], lrun[8], esc[8];
#pragma unroll
  for (int i = 0; i < 8; ++i) { mrun[i] = -1e30f; lrun[i] = 0.f; }

  const int lr8 = l >> 3, lc8 = (l & 7) ^ lr8;

  const int ntiles = 2 * qb + 2;
  for (int t = 0; t < ntiles; ++t) {
    const int k0 = t * 64;
    // stage K tile: rows=kv (256B), 16 chunks, swizzle on low-3 chunk bits
#pragma unroll
    for (int i = 0; i < 4; ++i) {
      int row = i * 16 + w * 4 + (l >> 4);
      int cko = (l & 15) ^ (row & 7);
      gload_lds16(Kb + (size_t)(k0 + row) * D + cko * 8,
                  (char*)Kl + (i * 16 + w * 4) * 256);
    }
    // stage Vt tile: rows=d (128B), 8 chunks
#pragma unroll
    for (int i = 0; i < 4; ++i) {
      int row = i * 32 + w * 8 + lr8;
      gload_lds16(Vb + (size_t)row * S + k0 + lc8 * 8,
                  (char*)Vl + (i * 32 + w * 8) * 128);
    }
    __syncthreads();

    const bool active = k0 < wq0 + 32;   // wave-uniform: any unmasked element?
    if (active) {
      // QK^T
      f32x4 sa[2][4] = {};
#pragma unroll
      for (int ks = 0; ks < 4; ++ks) {
        bf16x8 kf[4];
        int cc = ks * 4 + (l >> 4);
#pragma unroll
        for (int cf = 0; cf < 4; ++cf) {
          int row = cf * 16 + (l & 15);
          kf[cf] = *(const bf16x8*)((const char*)Kl + row * 256 +
                                    ((cc ^ (row & 7)) << 4));
        }
#pragma unroll
        for (int rg = 0; rg < 2; ++rg)
#pragma unroll
          for (int cf = 0; cf < 4; ++cf)
            sa[rg][cf] = __builtin_amdgcn_mfma_f32_16x16x32_bf16(
                qf[rg][ks], kf[cf], sa[rg][cf], 0, 0, 0);
      }

      // causal mask
      if (k0 + 63 > wq0) {
#pragma unroll
        for (int rg = 0; rg < 2; ++rg)
#pragma unroll
          for (int cf = 0; cf < 4; ++cf) {
            int kk = k0 + cf * 16 + (l & 15);
            int qrow = wq0 + rg * 16 + ((l >> 4) << 2);
#pragma unroll
            for (int r = 0; r < 4; ++r)
              if (qrow + r < kk) sa[rg][cf][r] = -1e9f;
          }
      }

      // online softmax
#pragma unroll
      for (int rg = 0; rg < 2; ++rg) {
        float tmax[4] = {-1e30f, -1e30f, -1e30f, -1e30f};
#pragma unroll
        for (int cf = 0; cf < 4; ++cf)
#pragma unroll
          for (int r = 0; r < 4; ++r)
            tmax[r] = fmaxf(tmax[r], sa[rg][cf][r]);
#pragma unroll
        for (int r = 0; r < 4; ++r) {
          tmax[r] = fmaxf(tmax[r], __shfl_xor(tmax[r], 1));
          tmax[r] = fmaxf(tmax[r], __shfl_xor(tmax[r], 2));
          tmax[r] = fmaxf(tmax[r], __shfl_xor(tmax[r], 4));
          tmax[r] = fmaxf(tmax[r], __shfl_xor(tmax[r], 8));
        }
        float rsum[4] = {0.f, 0.f, 0.f, 0.f};
#pragma unroll
        for (int r = 0; r < 4; ++r) {
          int idx = rg * 4 + r;
          float mnew = fmaxf(mrun[idx], tmax[r]);
          esc[idx] = __expf(mrun[idx] - mnew);
          mrun[idx] = mnew;
        }
#pragma unroll
        for (int cf = 0; cf < 4; ++cf)
#pragma unroll
          for (int r = 0; r < 4; ++r) {
            float p = __expf(sa[rg][cf][r] - mrun[rg * 4 + r]);
            sa[rg][cf][r] = p;
            rsum[r] += p;
          }
#pragma unroll
        for (int r = 0; r < 4; ++r) {
          rsum[r] += __shfl_xor(rsum[r], 1);
          rsum[r] += __shfl_xor(rsum[r], 2);
          rsum[r] += __shfl_xor(rsum[r], 4);
          rsum[r] += __shfl_xor(rsum[r], 8);
          int idx = rg * 4 + r;
          lrun[idx] = lrun[idx] * esc[idx] + rsum[r];
        }
      }
      // rescale O
#pragma unroll
      for (int rg = 0; rg < 2; ++rg)
#pragma unroll
        for (int df = 0; df < 8; ++df)
#pragma unroll
          for (int r = 0; r < 4; ++r)
            o[rg][df][r] *= esc[rg * 4 + r];

      // P -> LDS (bf16, swizzled)
      char* Pb = (char*)Pl[w];
#pragma unroll
      for (int rg = 0; rg < 2; ++rg)
#pragma unroll
        for (int cf = 0; cf < 4; ++cf) {
          int col = cf * 16 + (l & 15);
          int cchunk = col >> 3, cin = col & 7;
#pragma unroll
          for (int r = 0; r < 4; ++r) {
            int row = rg * 16 + ((l >> 4) << 2) + r;
            *(ushort*)(Pb + row * 128 + ((cchunk ^ (row & 7)) << 4) + cin * 2) =
                f2bf(sa[rg][cf][r]);
          }
        }

      // PV
#pragma unroll
      for (int ks = 0; ks < 2; ++ks) {
        bf16x8 pf[2];
        int cc = ks * 4 + (l >> 4);
#pragma unroll
        for (int rg = 0; rg < 2; ++rg) {
          int row = rg * 16 + (l & 15);
          pf[rg] = *(const bf16x8*)(Pb + row * 128 + ((cc ^ (row & 7)) << 4));
        }
#pragma unroll
        for (int df = 0; df < 8; ++df) {
          int row = df * 16 + (l & 15);
          bf16x8 vf = *(const bf16x8*)((const char*)Vl + row * 128 +
                                       ((cc ^ (row & 7)) << 4));
#pragma unroll
          for (int rg = 0; rg < 2; ++rg)
            o[rg][df] = __builtin_amdgcn_mfma_f32_16x16x32_bf16(
                pf[rg], vf, o[rg][df], 0, 0, 0);
        }
      }
    }
    __syncthreads();
  }

  // epilogue: divide by l, write combined [B][S][H*D]
  const int b = bh >> 4, h = bh & 15;
#pragma unroll
  for (int rg = 0; rg < 2; ++rg)
#pragma unroll
    for (int r = 0; r < 4; ++r) {
      int idx = rg * 4 + r;
      float inv = 1.0f / lrun[idx];
      int s = wq0 + rg * 16 + ((l >> 4) << 2) + r;
#pragma unroll
      for (int df = 0; df < 8; ++df) {
        int col = h * 128 + df * 16 + (l & 15);
        Og[((size_t)b * 2048 + s) * 2048 + col] = f2bf(o[rg][df][r] * inv);
      }
    }
}

// ---------------------------------------------------------------- launch
extern "C" void kernel_launch(void* const* d_in, const int* in_sizes, int n_in,
                              void* d_out, int out_size, void* d_ws,
                              size_t ws_size, hipStream_t stream) {
  const float* x = (const float*)d_in[0];
  const float* w_qkv = (const float*)d_in[1];
  const float* b_qkv = (const float*)d_in[2];
  const float* w_out = (const float*)d_in[3];
  const float* b_out = (const float*)d_in[4];
  float* out = (float*)d_out;
  char* ws = (char*)d_ws;

  // workspace layout (bytes):
  //   A: [0, 16MB)          x_bf16, later aliased by combined
  //   B: [16MB, 41MB)       w_qkv^T bf16, later aliased by w_out^T bf16
  //   C: Q   [41943040, +16MB)
  //   D: K   [58720256, +16MB)
  //   E: Vt  [75497472, +16MB)   total 92,274,688 B
  if (ws_size < 92274688u) return;
  ushort* xb = (ushort*)(ws);
  ushort* wqkvt = (ushort*)(ws + 16777216);
  ushort* Q = (ushort*)(ws + 41943040);
  ushort* Kb = (ushort*)(ws + 58720256);
  ushort* Vt = (ushort*)(ws + 75497472);
  ushort* comb = xb;
  ushort* woutt = wqkvt;

  // 1) x -> bf16
  cast_f32_bf16_kernel<<<8192, 256, 0, stream>>>((const float4*)x, (ushort4*)xb,
                                                 2097152);
  // 2) w_qkv^T bf16
  transpose_cast_kernel<<<dim3(96, 32), 256, 0, stream>>>(w_qkv, wqkvt, 2048,
                                                          6144);
  // 3) QKV GEMM + scatter
  gemm_bt_kernel<1><<<dim3(48, 32), 256, 0, stream>>>(
      xb, wqkvt, b_qkv, nullptr, Q, Kb, Vt, 4096, 6144, 2048);
  // 4) w_out^T bf16 (after GEMM1: aliases w_qkv^T region)
  transpose_cast_kernel<<<dim3(32, 32), 256, 0, stream>>>(w_out, woutt, 2048,
                                                          2048);
  // 5) attention (writes combined into region A; x_bf16 dead)
  attn_kernel<<<dim3(16, 32), 256, 0, stream>>>(Q, Kb, Vt, comb);
  // 6) output projection
  gemm_bt_kernel<0><<<dim3(16, 32), 256, 0, stream>>>(
      comb, woutt, b_out, out, nullptr, nullptr, nullptr, 4096, 2048, 2048);
}

// Round 2
// 261.904 us; speedup vs baseline: 1.1142x; 1.1142x over previous
//
#include <hip/hip_runtime.h>
#include <hip/hip_bf16.h>

typedef __attribute__((ext_vector_type(4))) float f32x4;
typedef __attribute__((ext_vector_type(8))) short bf16x8;

#define GBL_AS(p) (const __attribute__((address_space(1))) void*)(p)
#define LDS_AS(p) (__attribute__((address_space(3))) void*)(p)

__device__ __forceinline__ void gload_lds16(const void* g, void* l) {
  __builtin_amdgcn_global_load_lds(GBL_AS(g), LDS_AS(l), 16, 0, 0);
}

__device__ __forceinline__ ushort f2bf(float f) {
  union { float f; unsigned int u; } v; v.f = f;
  unsigned int r = v.u + 0x7fffu + ((v.u >> 16) & 1u);
  return (ushort)(r >> 16);
}

// ---------------------------------------------------------------- cast f32->bf16
__global__ void cast_f32_bf16_kernel(const float4* __restrict__ in,
                                     ushort4* __restrict__ out, int n4) {
  int i = blockIdx.x * 256 + threadIdx.x;
  if (i < n4) {
    float4 v = in[i];
    ushort4 o;
    o.x = f2bf(v.x); o.y = f2bf(v.y); o.z = f2bf(v.z); o.w = f2bf(v.w);
    out[i] = o;
  }
}

// ------------------------------------------------- transpose + cast: [R][C]f32 -> [C][R]bf16
__global__ void transpose_cast_kernel(const float* __restrict__ in,
                                      ushort* __restrict__ out, int R, int C) {
  __shared__ float tile[64][65];
  int tx = threadIdx.x & 63, ty = threadIdx.x >> 6;
  int r0 = blockIdx.y * 64, c0 = blockIdx.x * 64;
#pragma unroll
  for (int i = 0; i < 64; i += 4)
    tile[ty + i][tx] = in[(size_t)(r0 + ty + i) * C + (c0 + tx)];
  __syncthreads();
#pragma unroll
  for (int i = 0; i < 64; i += 4)
    out[(size_t)(c0 + ty + i) * R + (r0 + tx)] = f2bf(tile[tx][ty + i]);
}

// ---------------------------------------------------------------- bf16 GEMM, Bt layout
// A: [M][K] bf16, Bt: [N][K] bf16.  MODE 0: C=f32 [M][N] + bias.
// MODE 1: QKV scatter: Q scaled by 1/sqrt(128) -> [B*H][S][D]; K -> [B*H][S][D];
//         V -> transposed [B*H][D][S].  (HIDDEN=2048, H=16, D=128, S=2048 hard-coded)
template <int MODE>
__global__ __launch_bounds__(256, 2) void gemm_bt_kernel(
    const ushort* __restrict__ A, const ushort* __restrict__ Bt,
    const float* __restrict__ bias, float* __restrict__ C,
    ushort* __restrict__ Qo, ushort* __restrict__ Ko, ushort* __restrict__ Vo,
    int M, int N, int K) {
  __shared__ ushort As[128 * 64];
  __shared__ ushort Bs[128 * 64];
  const int tid = threadIdx.x;
  const int w = tid >> 6, l = tid & 63;
  const int wr = w >> 1, wc = w & 1;
  const int m0 = blockIdx.y * 128, n0 = blockIdx.x * 128;

  f32x4 acc[4][4] = {};

  const int lr = l >> 3;             // row-in-1KB-group (0..7)
  const int lc = (l & 7) ^ lr;       // pre-swizzled source chunk

  for (int k0 = 0; k0 < K; k0 += 64) {
#pragma unroll
    for (int i = 0; i < 4; ++i) {
      int row = i * 32 + w * 8 + lr;
      gload_lds16(A + (size_t)(m0 + row) * K + k0 + lc * 8,
                  (char*)As + (i * 32 + w * 8) * 128);
      gload_lds16(Bt + (size_t)(n0 + row) * K + k0 + lc * 8,
                  (char*)Bs + (i * 32 + w * 8) * 128);
    }
    __syncthreads();
    const char* Ab = (const char*)As;
    const char* Bb = (const char*)Bs;
#pragma unroll
    for (int ks = 0; ks < 2; ++ks) {
      bf16x8 af[4], bfr[4];
      int cc = ks * 4 + (l >> 4);
#pragma unroll
      for (int mi = 0; mi < 4; ++mi) {
        int row = wr * 64 + mi * 16 + (l & 15);
        af[mi] = *(const bf16x8*)(Ab + row * 128 + ((cc ^ (row & 7)) << 4));
      }
#pragma unroll
      for (int ni = 0; ni < 4; ++ni) {
        int row = wc * 64 + ni * 16 + (l & 15);
        bfr[ni] = *(const bf16x8*)(Bb + row * 128 + ((cc ^ (row & 7)) << 4));
      }
#pragma unroll
      for (int mi = 0; mi < 4; ++mi)
#pragma unroll
        for (int ni = 0; ni < 4; ++ni)
          acc[mi][ni] = __builtin_amdgcn_mfma_f32_16x16x32_bf16(
              af[mi], bfr[ni], acc[mi][ni], 0, 0, 0);
    }
    __syncthreads();
  }

  if (MODE == 0) {
#pragma unroll
    for (int mi = 0; mi < 4; ++mi) {
      int row = m0 + wr * 64 + mi * 16 + ((l >> 4) << 2);
#pragma unroll
      for (int ni = 0; ni < 4; ++ni) {
        int col = n0 + wc * 64 + ni * 16 + (l & 15);
        float b = bias[col];
#pragma unroll
        for (int r = 0; r < 4; ++r)
          C[(size_t)(row + r) * N + col] = acc[mi][ni][r] + b;
      }
    }
  } else {
    const float qscale = 0.08838834764831845f;  // 1/sqrt(128)
#pragma unroll
    for (int ni = 0; ni < 4; ++ni) {
      int n = n0 + wc * 64 + ni * 16 + (l & 15);
      int which = n >> 11;
      int cc2 = n & 2047;
      int h = cc2 >> 7, d = cc2 & 127;
      float b = bias[n];
#pragma unroll
      for (int mi = 0; mi < 4; ++mi) {
        int m = m0 + wr * 64 + mi * 16 + ((l >> 4) << 2);
        int bb = m >> 11, s = m & 2047;
        int bh = bb * 16 + h;
        if (which == 0) {
#pragma unroll
          for (int r = 0; r < 4; ++r)
            Qo[((size_t)bh * 2048 + s + r) * 128 + d] =
                f2bf((acc[mi][ni][r] + b) * qscale);
        } else if (which == 1) {
#pragma unroll
          for (int r = 0; r < 4; ++r)
            Ko[((size_t)bh * 2048 + s + r) * 128 + d] = f2bf(acc[mi][ni][r] + b);
        } else {
          ushort4 pk;
          pk.x = f2bf(acc[mi][ni][0] + b);
          pk.y = f2bf(acc[mi][ni][1] + b);
          pk.z = f2bf(acc[mi][ni][2] + b);
          pk.w = f2bf(acc[mi][ni][3] + b);
          *(ushort4*)(Vo + ((size_t)bh * 128 + d) * 2048 + s) = pk;
        }
      }
    }
  }
}

// ---------------------------------------------------------------- flash attention
// Q,K: [B*H][S][D] bf16 (Q pre-scaled);  Vt: [B*H][D][S] bf16.
// Out: combined [B][S][H*D] bf16.
// 8-wave blocks: waves 0-3 handle qb=8+j, waves 4-7 handle qb=7-j (balanced:
// 34 wave-tiles per SIMD, constant). K/V double-buffered, counted vmcnt.
__global__ __launch_bounds__(512, 2) void attn_kernel(
    const ushort* __restrict__ Qg, const ushort* __restrict__ Kg,
    const ushort* __restrict__ Vtg, ushort* __restrict__ Og) {
  constexpr int S = 2048, D = 128;
  __shared__ ushort Kl[2][64 * 128];   // [kv][d], 256B rows, swizzled
  __shared__ ushort Vl[2][128 * 64];   // [d][kv], 128B rows, swizzled
  __shared__ ushort Pl[8][32 * 64];    // per-wave P, swizzled

  const int tid = threadIdx.x, w = tid >> 6, l = tid & 63;
  const int lid = blockIdx.x;
  const int bh = lid & 31;            // same-bh blocks share an XCD (lid%8 = bh%8)
  const int j = lid >> 5;             // pair index 0..7
  const int g = w >> 2, wv = w & 3;
  const int qb = (g == 0) ? (8 + j) : (7 - j);
  const int wq0 = qb * 128 + wv * 32;
  const int nt_blk = 18 + 2 * j;      // tiles staged = heavy wave's need

  const ushort* Qb = Qg + (size_t)bh * S * D;
  const ushort* Kb = Kg + (size_t)bh * S * D;
  const ushort* Vb = Vtg + (size_t)bh * D * S;

  bf16x8 qf[2][4];
#pragma unroll
  for (int rg = 0; rg < 2; ++rg)
#pragma unroll
    for (int ks = 0; ks < 4; ++ks)
      qf[rg][ks] = *(const bf16x8*)(Qb + (size_t)(wq0 + rg * 16 + (l & 15)) * D +
                                    ks * 32 + (l >> 4) * 8);

  f32x4 o[2][8] = {};
  float mrun[8], lrun[8], esc[8];
#pragma unroll
  for (int i = 0; i < 8; ++i) { mrun[i] = -1e30f; lrun[i] = 0.f; }

  // stage one 64-kv tile (4 gload_lds16 per wave: 2 K + 2 V)
  auto stage = [&](int t, int buf) {
    const int k0 = t * 64;
#pragma unroll
    for (int s2 = 0; s2 < 2; ++s2) {
      int i = w * 2 + s2;
      int row = i * 4 + (l >> 4);
      int ck = (l & 15) ^ (row & 7);
      gload_lds16(Kb + (size_t)(k0 + row) * D + ck * 8,
                  (char*)Kl[buf] + i * 1024);
    }
#pragma unroll
    for (int s2 = 0; s2 < 2; ++s2) {
      int i = w * 2 + s2;
      int row = i * 8 + (l >> 3);
      int ck = (l & 7) ^ (row & 7);
      gload_lds16(Vb + (size_t)row * S + k0 + ck * 8,
                  (char*)Vl[buf] + i * 1024);
    }
  };

  stage(0, 0);

  for (int t = 0; t < nt_blk; ++t) {
    const int cur = t & 1;
    const int k0 = t * 64;
    if (t + 1 < nt_blk) {
      stage(t + 1, cur ^ 1);
      asm volatile("s_waitcnt vmcnt(4)" ::: "memory");
    } else {
      asm volatile("s_waitcnt vmcnt(0)" ::: "memory");
    }
    __builtin_amdgcn_s_barrier();

    const bool active = k0 < wq0 + 32;   // wave-uniform
    if (active) {
      const char* Kc = (const char*)Kl[cur];
      const char* Vc = (const char*)Vl[cur];
      // QK^T
      f32x4 sa[2][4] = {};
#pragma unroll
      for (int ks = 0; ks < 4; ++ks) {
        bf16x8 kf[4];
        int cc = ks * 4 + (l >> 4);
#pragma unroll
        for (int cf = 0; cf < 4; ++cf) {
          int row = cf * 16 + (l & 15);
          kf[cf] = *(const bf16x8*)(Kc + row * 256 + ((cc ^ (row & 7)) << 4));
        }
        __builtin_amdgcn_s_setprio(1);
#pragma unroll
        for (int rg = 0; rg < 2; ++rg)
#pragma unroll
          for (int cf = 0; cf < 4; ++cf)
            sa[rg][cf] = __builtin_amdgcn_mfma_f32_16x16x32_bf16(
                qf[rg][ks], kf[cf], sa[rg][cf], 0, 0, 0);
        __builtin_amdgcn_s_setprio(0);
      }

      // causal mask
      if (k0 + 63 > wq0) {
#pragma unroll
        for (int rg = 0; rg < 2; ++rg)
#pragma unroll
          for (int cf = 0; cf < 4; ++cf) {
            int kk = k0 + cf * 16 + (l & 15);
            int qrow = wq0 + rg * 16 + ((l >> 4) << 2);
#pragma unroll
            for (int r = 0; r < 4; ++r)
              if (qrow + r < kk) sa[rg][cf][r] = -1e9f;
          }
      }

      // online softmax
#pragma unroll
      for (int rg = 0; rg < 2; ++rg) {
        float tmax[4] = {-1e30f, -1e30f, -1e30f, -1e30f};
#pragma unroll
        for (int cf = 0; cf < 4; ++cf)
#pragma unroll
          for (int r = 0; r < 4; ++r)
            tmax[r] = fmaxf(tmax[r], sa[rg][cf][r]);
#pragma unroll
        for (int r = 0; r < 4; ++r) {
          tmax[r] = fmaxf(tmax[r], __shfl_xor(tmax[r], 1));
          tmax[r] = fmaxf(tmax[r], __shfl_xor(tmax[r], 2));
          tmax[r] = fmaxf(tmax[r], __shfl_xor(tmax[r], 4));
          tmax[r] = fmaxf(tmax[r], __shfl_xor(tmax[r], 8));
        }
        float rsum[4] = {0.f, 0.f, 0.f, 0.f};
#pragma unroll
        for (int r = 0; r < 4; ++r) {
          int idx = rg * 4 + r;
          float mnew = fmaxf(mrun[idx], tmax[r]);
          esc[idx] = __expf(mrun[idx] - mnew);
          mrun[idx] = mnew;
        }
#pragma unroll
        for (int cf = 0; cf < 4; ++cf)
#pragma unroll
          for (int r = 0; r < 4; ++r) {
            float p = __expf(sa[rg][cf][r] - mrun[rg * 4 + r]);
            sa[rg][cf][r] = p;
            rsum[r] += p;
          }
#pragma unroll
        for (int r = 0; r < 4; ++r) {
          rsum[r] += __shfl_xor(rsum[r], 1);
          rsum[r] += __shfl_xor(rsum[r], 2);
          rsum[r] += __shfl_xor(rsum[r], 4);
          rsum[r] += __shfl_xor(rsum[r], 8);
          int idx = rg * 4 + r;
          lrun[idx] = lrun[idx] * esc[idx] + rsum[r];
        }
      }
      // rescale O
#pragma unroll
      for (int rg = 0; rg < 2; ++rg)
#pragma unroll
        for (int df = 0; df < 8; ++df)
#pragma unroll
          for (int r = 0; r < 4; ++r)
            o[rg][df][r] *= esc[rg * 4 + r];

      // P -> LDS (bf16, swizzled)
      char* Pb = (char*)Pl[w];
#pragma unroll
      for (int rg = 0; rg < 2; ++rg)
#pragma unroll
        for (int cf = 0; cf < 4; ++cf) {
          int col = cf * 16 + (l & 15);
          int cchunk = col >> 3, cin = col & 7;
#pragma unroll
          for (int r = 0; r < 4; ++r) {
            int row = rg * 16 + ((l >> 4) << 2) + r;
            *(ushort*)(Pb + row * 128 + ((cchunk ^ (row & 7)) << 4) + cin * 2) =
                f2bf(sa[rg][cf][r]);
          }
        }

      // PV
#pragma unroll
      for (int ks = 0; ks < 2; ++ks) {
        bf16x8 pf[2];
        int cc = ks * 4 + (l >> 4);
#pragma unroll
        for (int rg = 0; rg < 2; ++rg) {
          int row = rg * 16 + (l & 15);
          pf[rg] = *(const bf16x8*)(Pb + row * 128 + ((cc ^ (row & 7)) << 4));
        }
        bf16x8 vf[8];
#pragma unroll
        for (int df = 0; df < 8; ++df) {
          int row = df * 16 + (l & 15);
          vf[df] = *(const bf16x8*)(Vc + row * 128 + ((cc ^ (row & 7)) << 4));
        }
        __builtin_amdgcn_s_setprio(1);
#pragma unroll
        for (int df = 0; df < 8; ++df)
#pragma unroll
          for (int rg = 0; rg < 2; ++rg)
            o[rg][df] = __builtin_amdgcn_mfma_f32_16x16x32_bf16(
                pf[rg], vf[df], o[rg][df], 0, 0, 0);
        __builtin_amdgcn_s_setprio(0);
      }
    }
    asm volatile("s_waitcnt lgkmcnt(0)" ::: "memory");
    __builtin_amdgcn_s_barrier();
  }

  // epilogue: divide by l, write combined [B][S][H*D]
  const int b = bh >> 4, h = bh & 15;
#pragma unroll
  for (int rg = 0; rg < 2; ++rg)
#pragma unroll
    for (int r = 0; r < 4; ++r) {
      int idx = rg * 4 + r;
      float inv = 1.0f / lrun[idx];
      int s = wq0 + rg * 16 + ((l >> 4) << 2) + r;
#pragma unroll
      for (int df = 0; df < 8; ++df) {
        int col = h * 128 + df * 16 + (l & 15);
        Og[((size_t)b * 2048 + s) * 2048 + col] = f2bf(o[rg][df][r] * inv);
      }
    }
}

// ---------------------------------------------------------------- launch
extern "C" void kernel_launch(void* const* d_in, const int* in_sizes, int n_in,
                              void* d_out, int out_size, void* d_ws,
                              size_t ws_size, hipStream_t stream) {
  const float* x = (const float*)d_in[0];
  const float* w_qkv = (const float*)d_in[1];
  const float* b_qkv = (const float*)d_in[2];
  const float* w_out = (const float*)d_in[3];
  const float* b_out = (const float*)d_in[4];
  float* out = (float*)d_out;
  char* ws = (char*)d_ws;

  // workspace layout (bytes):
  //   A: [0, 16MB)          x_bf16, later aliased by combined
  //   B: [16MB, 41MB)       w_qkv^T bf16, later aliased by w_out^T bf16
  //   C: Q   [41943040, +16MB)
  //   D: K   [58720256, +16MB)
  //   E: Vt  [75497472, +16MB)   total 92,274,688 B
  if (ws_size < 92274688u) return;
  ushort* xb = (ushort*)(ws);
  ushort* wqkvt = (ushort*)(ws + 16777216);
  ushort* Q = (ushort*)(ws + 41943040);
  ushort* Kb = (ushort*)(ws + 58720256);
  ushort* Vt = (ushort*)(ws + 75497472);
  ushort* comb = xb;
  ushort* woutt = wqkvt;

  // 1) x -> bf16
  cast_f32_bf16_kernel<<<8192, 256, 0, stream>>>((const float4*)x, (ushort4*)xb,
                                                 2097152);
  // 2) w_qkv^T bf16
  transpose_cast_kernel<<<dim3(96, 32), 256, 0, stream>>>(w_qkv, wqkvt, 2048,
                                                          6144);
  // 3) QKV GEMM + scatter
  gemm_bt_kernel<1><<<dim3(48, 32), 256, 0, stream>>>(
      xb, wqkvt, b_qkv, nullptr, Q, Kb, Vt, 4096, 6144, 2048);
  // 4) w_out^T bf16 (after GEMM1: aliases w_qkv^T region)
  transpose_cast_kernel<<<dim3(32, 32), 256, 0, stream>>>(w_out, woutt, 2048,
                                                          2048);
  // 5) attention (writes combined into region A; x_bf16 dead)
  attn_kernel<<<dim3(256), 512, 0, stream>>>(Q, Kb, Vt, comb);
  // 6) output projection
  gemm_bt_kernel<0><<<dim3(16, 32), 256, 0, stream>>>(
      comb, woutt, b_out, out, nullptr, nullptr, nullptr, 4096, 2048, 2048);
}

// Round 3
// 233.691 us; speedup vs baseline: 1.2487x; 1.1207x over previous
//
#include <hip/hip_runtime.h>
#include <hip/hip_bf16.h>

typedef __attribute__((ext_vector_type(4))) float f32x4;
typedef __attribute__((ext_vector_type(16))) float f32x16;
typedef __attribute__((ext_vector_type(8))) short bf16x8;

#define GBL_AS(p) (const __attribute__((address_space(1))) void*)(p)
#define LDS_AS(p) (__attribute__((address_space(3))) void*)(p)

__device__ __forceinline__ void gload_lds16(const void* g, void* l) {
  __builtin_amdgcn_global_load_lds(GBL_AS(g), LDS_AS(l), 16, 0, 0);
}

__device__ __forceinline__ ushort f2bf(float f) {
  union { float f; unsigned int u; } v; v.f = f;
  unsigned int r = v.u + 0x7fffu + ((v.u >> 16) & 1u);
  return (ushort)(r >> 16);
}

// ---------------------------------------------------------------- cast f32->bf16
__global__ void cast_f32_bf16_kernel(const float4* __restrict__ in,
                                     ushort4* __restrict__ out, int n4) {
  int i = blockIdx.x * 256 + threadIdx.x;
  if (i < n4) {
    float4 v = in[i];
    ushort4 o;
    o.x = f2bf(v.x); o.y = f2bf(v.y); o.z = f2bf(v.z); o.w = f2bf(v.w);
    out[i] = o;
  }
}

// ------------------------------------------------- transpose + cast: [R][C]f32 -> [C][R]bf16
__global__ void transpose_cast_kernel(const float* __restrict__ in,
                                      ushort* __restrict__ out, int R, int C) {
  __shared__ float tile[64][65];
  int tx = threadIdx.x & 63, ty = threadIdx.x >> 6;
  int r0 = blockIdx.y * 64, c0 = blockIdx.x * 64;
#pragma unroll
  for (int i = 0; i < 64; i += 4)
    tile[ty + i][tx] = in[(size_t)(r0 + ty + i) * C + (c0 + tx)];
  __syncthreads();
#pragma unroll
  for (int i = 0; i < 64; i += 4)
    out[(size_t)(c0 + ty + i) * R + (r0 + tx)] = f2bf(tile[tx][ty + i]);
}

// ---------------------------------------------------------------- bf16 GEMM, Bt layout
template <int MODE>
__global__ __launch_bounds__(256, 2) void gemm_bt_kernel(
    const ushort* __restrict__ A, const ushort* __restrict__ Bt,
    const float* __restrict__ bias, float* __restrict__ C,
    ushort* __restrict__ Qo, ushort* __restrict__ Ko, ushort* __restrict__ Vo,
    int M, int N, int K) {
  __shared__ ushort As[128 * 64];
  __shared__ ushort Bs[128 * 64];
  const int tid = threadIdx.x;
  const int w = tid >> 6, l = tid & 63;
  const int wr = w >> 1, wc = w & 1;
  const int m0 = blockIdx.y * 128, n0 = blockIdx.x * 128;

  f32x4 acc[4][4] = {};

  const int lr = l >> 3;
  const int lc = (l & 7) ^ lr;

  for (int k0 = 0; k0 < K; k0 += 64) {
#pragma unroll
    for (int i = 0; i < 4; ++i) {
      int row = i * 32 + w * 8 + lr;
      gload_lds16(A + (size_t)(m0 + row) * K + k0 + lc * 8,
                  (char*)As + (i * 32 + w * 8) * 128);
      gload_lds16(Bt + (size_t)(n0 + row) * K + k0 + lc * 8,
                  (char*)Bs + (i * 32 + w * 8) * 128);
    }
    __syncthreads();
    const char* Ab = (const char*)As;
    const char* Bb = (const char*)Bs;
#pragma unroll
    for (int ks = 0; ks < 2; ++ks) {
      bf16x8 af[4], bfr[4];
      int cc = ks * 4 + (l >> 4);
#pragma unroll
      for (int mi = 0; mi < 4; ++mi) {
        int row = wr * 64 + mi * 16 + (l & 15);
        af[mi] = *(const bf16x8*)(Ab + row * 128 + ((cc ^ (row & 7)) << 4));
      }
#pragma unroll
      for (int ni = 0; ni < 4; ++ni) {
        int row = wc * 64 + ni * 16 + (l & 15);
        bfr[ni] = *(const bf16x8*)(Bb + row * 128 + ((cc ^ (row & 7)) << 4));
      }
#pragma unroll
      for (int mi = 0; mi < 4; ++mi)
#pragma unroll
        for (int ni = 0; ni < 4; ++ni)
          acc[mi][ni] = __builtin_amdgcn_mfma_f32_16x16x32_bf16(
              af[mi], bfr[ni], acc[mi][ni], 0, 0, 0);
    }
    __syncthreads();
  }

  if (MODE == 0) {
#pragma unroll
    for (int mi = 0; mi < 4; ++mi) {
      int row = m0 + wr * 64 + mi * 16 + ((l >> 4) << 2);
#pragma unroll
      for (int ni = 0; ni < 4; ++ni) {
        int col = n0 + wc * 64 + ni * 16 + (l & 15);
        float b = bias[col];
#pragma unroll
        for (int r = 0; r < 4; ++r)
          C[(size_t)(row + r) * N + col] = acc[mi][ni][r] + b;
      }
    }
  } else {
    const float qscale = 0.08838834764831845f;  // 1/sqrt(128)
#pragma unroll
    for (int ni = 0; ni < 4; ++ni) {
      int n = n0 + wc * 64 + ni * 16 + (l & 15);
      int which = n >> 11;
      int cc2 = n & 2047;
      int h = cc2 >> 7, d = cc2 & 127;
      float b = bias[n];
#pragma unroll
      for (int mi = 0; mi < 4; ++mi) {
        int m = m0 + wr * 64 + mi * 16 + ((l >> 4) << 2);
        int bb = m >> 11, s = m & 2047;
        int bh = bb * 16 + h;
        if (which == 0) {
#pragma unroll
          for (int r = 0; r < 4; ++r)
            Qo[((size_t)bh * 2048 + s + r) * 128 + d] =
                f2bf((acc[mi][ni][r] + b) * qscale);
        } else if (which == 1) {
#pragma unroll
          for (int r = 0; r < 4; ++r)
            Ko[((size_t)bh * 2048 + s + r) * 128 + d] = f2bf(acc[mi][ni][r] + b);
        } else {
          ushort4 pk;
          pk.x = f2bf(acc[mi][ni][0] + b);
          pk.y = f2bf(acc[mi][ni][1] + b);
          pk.z = f2bf(acc[mi][ni][2] + b);
          pk.w = f2bf(acc[mi][ni][3] + b);
          *(ushort4*)(Vo + ((size_t)bh * 128 + d) * 2048 + s) = pk;
        }
      }
    }
  }
}

// ---------------------------------------------------------------- flash attention
// Swapped-QK^T design: S^T = mfma_32x32x16(A=K, B=Q) so each lane owns one
// q-row (q = lane&31); softmax is in-register (1 shfl per reduce); P->bf16
// via v_cvt_pk + permlane32_swap feeds PV directly as B-operand; O kept as
// O^T = mfma(A=Vt, B=P^T). No P LDS bounce. LDS = 64KB (K,V dbuf only).
__global__ __launch_bounds__(512, 2) void attn_kernel(
    const ushort* __restrict__ Qg, const ushort* __restrict__ Kg,
    const ushort* __restrict__ Vtg, ushort* __restrict__ Og) {
  constexpr int S = 2048, D = 128;
  __shared__ ushort Kl[2][64 * 128];   // [kv][d], 256B rows, chunk-swizzled
  __shared__ ushort Vl[2][128 * 64];   // [d][kv], 128B rows, chunk-swizzled

  const int tid = threadIdx.x, w = tid >> 6, l = tid & 63;
  const int lid = blockIdx.x;
  const int bh = lid & 31;            // same-bh blocks share an XCD
  const int j = lid >> 5;             // pair index 0..7
  const int g = w >> 2, wv = w & 3;
  const int qb = (g == 0) ? (8 + j) : (7 - j);
  const int wq0 = qb * 128 + wv * 32;
  const int nt_blk = 18 + 2 * j;
  const int ql = l & 31, h32 = l >> 5;

  const ushort* Qb = Qg + (size_t)bh * S * D;
  const ushort* Kb = Kg + (size_t)bh * S * D;
  const ushort* Vb = Vtg + (size_t)bh * D * S;

  // Q fragment (B-operand): lane holds Q[wq0+ql][ks*16 + h32*8 .. +7]
  bf16x8 qf[8];
#pragma unroll
  for (int ks = 0; ks < 8; ++ks)
    qf[ks] = *(const bf16x8*)(Qb + (size_t)(wq0 + ql) * D + ks * 16 + h32 * 8);

  f32x16 o[4];
#pragma unroll
  for (int dt = 0; dt < 4; ++dt) o[dt] = 0.f;
  float mrun = -1e30f, lrun = 0.f;

  auto stage = [&](int t, int buf) {
    const int k0 = t * 64;
#pragma unroll
    for (int s2 = 0; s2 < 2; ++s2) {
      int i = w * 2 + s2;
      int row = i * 4 + (l >> 4);
      int ck = (l & 15) ^ (row & 7);
      gload_lds16(Kb + (size_t)(k0 + row) * D + ck * 8,
                  (char*)Kl[buf] + i * 1024);
    }
#pragma unroll
    for (int s2 = 0; s2 < 2; ++s2) {
      int i = w * 2 + s2;
      int row = i * 8 + (l >> 3);
      int ck = (l & 7) ^ (row & 7);
      gload_lds16(Vb + (size_t)row * S + k0 + ck * 8,
                  (char*)Vl[buf] + i * 1024);
    }
  };

  stage(0, 0);

  for (int t = 0; t < nt_blk; ++t) {
    const int cur = t & 1;
    const int k0 = t * 64;
    if (t + 1 < nt_blk) {
      stage(t + 1, cur ^ 1);
      asm volatile("s_waitcnt vmcnt(4)" ::: "memory");
    } else {
      asm volatile("s_waitcnt vmcnt(0)" ::: "memory");
    }
    __builtin_amdgcn_s_barrier();

    if (k0 < wq0 + 32) {                 // wave-uniform causal activity
      const char* Kc = (const char*)Kl[cur];
      const char* Vc = (const char*)Vl[cur];

      // ---- QK^T (swapped): sa[kt] = S^T tile, lane q=ql, k=crow(reg,h32)
      f32x16 sa[2];
#pragma unroll
      for (int kt = 0; kt < 2; ++kt) sa[kt] = 0.f;
      __builtin_amdgcn_s_setprio(1);
#pragma unroll
      for (int kt = 0; kt < 2; ++kt) {
        int row = kt * 32 + ql;
        int swz = row & 7;
#pragma unroll
        for (int ks = 0; ks < 8; ++ks) {
          int c = 2 * ks + h32;
          bf16x8 kf = *(const bf16x8*)(Kc + row * 256 + ((c ^ swz) << 4));
          sa[kt] = __builtin_amdgcn_mfma_f32_32x32x16_bf16(kf, qf[ks], sa[kt],
                                                           0, 0, 0);
        }
      }
      __builtin_amdgcn_s_setprio(0);

      // ---- causal mask (only straddling tiles)
      if (k0 + 63 > wq0) {
        int q = wq0 + ql;
#pragma unroll
        for (int kt = 0; kt < 2; ++kt) {
          int kb = k0 + kt * 32 + 4 * h32;
#pragma unroll
          for (int r = 0; r < 16; ++r) {
            int kk = kb + (r & 3) + 8 * (r >> 2);
            if (q < kk) sa[kt][r] = -1e9f;
          }
        }
      }

      // ---- online softmax (lane-local row; 1 shfl per reduce)
      float tmax = -1e30f;
#pragma unroll
      for (int kt = 0; kt < 2; ++kt)
#pragma unroll
        for (int r = 0; r < 16; ++r) tmax = fmaxf(tmax, sa[kt][r]);
      tmax = fmaxf(tmax, __shfl_xor(tmax, 32));
      float mnew = fmaxf(mrun, tmax);
      float e = __expf(mrun - mnew);
      float rsum = 0.f;
#pragma unroll
      for (int kt = 0; kt < 2; ++kt)
#pragma unroll
        for (int r = 0; r < 16; ++r) {
          float p = __expf(sa[kt][r] - mnew);
          sa[kt][r] = p;
          rsum += p;
        }
      rsum += __shfl_xor(rsum, 32);
      lrun = lrun * e + rsum;
      mrun = mnew;
#pragma unroll
      for (int dt = 0; dt < 4; ++dt) o[dt] *= e;

      // ---- P->bf16 (cvt_pk) + permlane32_swap -> PV B-frags; PV MFMAs
#pragma unroll
      for (int kt = 0; kt < 2; ++kt) {
#pragma unroll
        for (int u = 0; u < 2; ++u) {
          int A0, B0, A1, B1;
          asm("v_cvt_pk_bf16_f32 %0, %1, %2"
              : "=v"(A0) : "v"(sa[kt][u * 8 + 0]), "v"(sa[kt][u * 8 + 1]));
          asm("v_cvt_pk_bf16_f32 %0, %1, %2"
              : "=v"(B0) : "v"(sa[kt][u * 8 + 2]), "v"(sa[kt][u * 8 + 3]));
          asm("v_cvt_pk_bf16_f32 %0, %1, %2"
              : "=v"(A1) : "v"(sa[kt][u * 8 + 4]), "v"(sa[kt][u * 8 + 5]));
          asm("v_cvt_pk_bf16_f32 %0, %1, %2"
              : "=v"(B1) : "v"(sa[kt][u * 8 + 6]), "v"(sa[kt][u * 8 + 7]));
          auto r02 = __builtin_amdgcn_permlane32_swap(A0, A1, false, false);
          auto r13 = __builtin_amdgcn_permlane32_swap(B0, B1, false, false);
          union { int i[4]; bf16x8 v; } pu;
          pu.i[0] = r02[0];  // j01: k = 8h+0,1
          pu.i[1] = r13[0];  // j23
          pu.i[2] = r02[1];  // j45
          pu.i[3] = r13[1];  // j67
          int c = 4 * kt + 2 * u + h32;
          __builtin_amdgcn_s_setprio(1);
#pragma unroll
          for (int dt = 0; dt < 4; ++dt) {
            int row = dt * 32 + ql;
            bf16x8 vf = *(const bf16x8*)(Vc + row * 128 + ((c ^ (row & 7)) << 4));
            o[dt] = __builtin_amdgcn_mfma_f32_32x32x16_bf16(vf, pu.v, o[dt],
                                                            0, 0, 0);
          }
          __builtin_amdgcn_s_setprio(0);
        }
      }
    }
    asm volatile("s_waitcnt lgkmcnt(0)" ::: "memory");
    __builtin_amdgcn_s_barrier();
  }

  // ---- epilogue: O^T regs -> combined [B][S][H*D]; lane owns row s=wq0+ql
  const int b = bh >> 4, h = bh & 15;
  float inv = 1.0f / lrun;
  size_t rowbase = ((size_t)b * 2048 + (wq0 + ql)) * 2048 + h * 128;
#pragma unroll
  for (int dt = 0; dt < 4; ++dt)
#pragma unroll
    for (int r4 = 0; r4 < 4; ++r4) {
      int col = dt * 32 + r4 * 8 + h32 * 4;
      ushort4 pk;
      pk.x = f2bf(o[dt][r4 * 4 + 0] * inv);
      pk.y = f2bf(o[dt][r4 * 4 + 1] * inv);
      pk.z = f2bf(o[dt][r4 * 4 + 2] * inv);
      pk.w = f2bf(o[dt][r4 * 4 + 3] * inv);
      *(ushort4*)(Og + rowbase + col) = pk;
    }
}

// ---------------------------------------------------------------- launch
extern "C" void kernel_launch(void* const* d_in, const int* in_sizes, int n_in,
                              void* d_out, int out_size, void* d_ws,
                              size_t ws_size, hipStream_t stream) {
  const float* x = (const float*)d_in[0];
  const float* w_qkv = (const float*)d_in[1];
  const float* b_qkv = (const float*)d_in[2];
  const float* w_out = (const float*)d_in[3];
  const float* b_out = (const float*)d_in[4];
  float* out = (float*)d_out;
  char* ws = (char*)d_ws;

  if (ws_size < 92274688u) return;
  ushort* xb = (ushort*)(ws);
  ushort* wqkvt = (ushort*)(ws + 16777216);
  ushort* Q = (ushort*)(ws + 41943040);
  ushort* Kb = (ushort*)(ws + 58720256);
  ushort* Vt = (ushort*)(ws + 75497472);
  ushort* comb = xb;
  ushort* woutt = wqkvt;

  cast_f32_bf16_kernel<<<8192, 256, 0, stream>>>((const float4*)x, (ushort4*)xb,
                                                 2097152);
  transpose_cast_kernel<<<dim3(96, 32), 256, 0, stream>>>(w_qkv, wqkvt, 2048,
                                                          6144);
  gemm_bt_kernel<1><<<dim3(48, 32), 256, 0, stream>>>(
      xb, wqkvt, b_qkv, nullptr, Q, Kb, Vt, 4096, 6144, 2048);
  transpose_cast_kernel<<<dim3(32, 32), 256, 0, stream>>>(w_out, woutt, 2048,
                                                          2048);
  attn_kernel<<<dim3(256), 512, 0, stream>>>(Q, Kb, Vt, comb);
  gemm_bt_kernel<0><<<dim3(16, 32), 256, 0, stream>>>(
      comb, woutt, b_out, out, nullptr, nullptr, nullptr, 4096, 2048, 2048);
}